// Round 1
// baseline (767.942 us; speedup 1.0000x reference)
//
#include <hip/hip_runtime.h>
#include <hip/hip_bf16.h>
#include <stdint.h>

#define LSZ 768
#define FD  128
#define PD  32
#define LLF (LSZ*LSZ)

typedef __attribute__((ext_vector_type(8))) short bf16x8;
typedef __attribute__((ext_vector_type(4))) float f32x4;

__device__ __forceinline__ unsigned short f2bf(float x) {
    union { float f; uint32_t u; } v; v.f = x;
    return (unsigned short)((v.u + 0x7FFFu + ((v.u >> 16) & 1u)) >> 16);
}
__device__ __forceinline__ uint32_t pack2(float a, float b) {
    return (uint32_t)f2bf(a) | ((uint32_t)f2bf(b) << 16);
}
__device__ __forceinline__ float sigm(float x) { return 1.0f / (1.0f + __expf(-x)); }

// ---------------------------------------------------------------------------
// Kernel A: x = LN(features); proj = (x@aW.T+ab)*sigmoid(x@agW.T+agb)
// Writes proj as bf16, channel-major: proj[c][r], r = i*768+l.
// W2 = [aW; agW] stacked (64x128): wave computes 32 rows x 64 cols so each
// lane holds the a-dot (n=0,1) and g-dot (n=2,3) for the same channel.
// ---------------------------------------------------------------------------
__global__ __launch_bounds__(256, 2) void k_ln_proj(
    const float* __restrict__ feat, const float* __restrict__ nw, const float* __restrict__ nb,
    const float* __restrict__ aW, const float* __restrict__ ab,
    const float* __restrict__ agW, const float* __restrict__ agb,
    unsigned short* __restrict__ proj)
{
    __shared__ unsigned short xb[128*128];   // bf16, XOR-swizzled 16B units
    __shared__ unsigned short w2[64*128];    // bf16, XOR-swizzled
    __shared__ unsigned short pbuf[32*136];  // proj transpose buffer

    const int t = threadIdx.x;
    const int rbase = blockIdx.x << 7;

    // stage W2 = [aW ; agW] as bf16 (swizzled units of 8 elems)
    for (int u = t; u < 64*16; u += 256) {
        const int r = u >> 4, c8 = u & 15;
        const float* src = (r < 32 ? aW + r*128 : agW + (r-32)*128) + c8*8;
        float4 f0 = *(const float4*)(src);
        float4 f1 = *(const float4*)(src + 4);
        uint4 o;
        o.x = pack2(f0.x, f0.y); o.y = pack2(f0.z, f0.w);
        o.z = pack2(f1.x, f1.y); o.w = pack2(f1.z, f1.w);
        *(uint4*)(&w2[r*128 + ((c8 ^ (r & 15)) << 3)]) = o;
    }

    // LayerNorm over F=128: 2 threads per row, 64 elems each, held in regs
    {
        const int row = t >> 1, sub = t & 1;
        const float* frow = feat + (size_t)(rbase + row)*FD + sub*64;
        float4 v[16];
        float s1 = 0.f, s2 = 0.f;
        #pragma unroll
        for (int q = 0; q < 16; ++q) {
            v[q] = *(const float4*)(frow + q*4);
            s1 += v[q].x + v[q].y + v[q].z + v[q].w;
            s2 += v[q].x*v[q].x + v[q].y*v[q].y + v[q].z*v[q].z + v[q].w*v[q].w;
        }
        s1 += __shfl_xor(s1, 1);
        s2 += __shfl_xor(s2, 1);
        const float mu = s1 * (1.f/128.f);
        const float rstd = rsqrtf(s2 * (1.f/128.f) - mu*mu + 1e-5f);
        #pragma unroll
        for (int q = 0; q < 8; ++q) {
            const int k = sub*64 + q*8;
            float4 w0 = *(const float4*)(nw + k), w1 = *(const float4*)(nw + k + 4);
            float4 b0 = *(const float4*)(nb + k), b1 = *(const float4*)(nb + k + 4);
            float4 x0 = v[2*q], x1 = v[2*q+1];
            uint4 o;
            o.x = pack2((x0.x-mu)*rstd*w0.x + b0.x, (x0.y-mu)*rstd*w0.y + b0.y);
            o.y = pack2((x0.z-mu)*rstd*w0.z + b0.z, (x0.w-mu)*rstd*w0.w + b0.w);
            o.z = pack2((x1.x-mu)*rstd*w1.x + b1.x, (x1.y-mu)*rstd*w1.y + b1.y);
            o.w = pack2((x1.z-mu)*rstd*w1.z + b1.z, (x1.w-mu)*rstd*w1.w + b1.w);
            const int c8 = k >> 3;
            *(uint4*)(&xb[row*128 + ((c8 ^ (row & 15)) << 3)]) = o;
        }
    }
    __syncthreads();

    // MFMA: [128 rows x 64 cols] = xb[128,128] @ w2[64,128]^T, K=128
    const int lane = t & 63, wid = t >> 6;
    const int lrow = lane & 15, g = lane >> 4;
    f32x4 acc[2][4];
    #pragma unroll
    for (int m = 0; m < 2; ++m)
        #pragma unroll
        for (int n = 0; n < 4; ++n) acc[m][n] = (f32x4){0.f,0.f,0.f,0.f};

    #pragma unroll
    for (int kk = 0; kk < 4; ++kk) {
        bf16x8 a[2], b[4];
        #pragma unroll
        for (int m = 0; m < 2; ++m) {
            const int r = wid*32 + m*16 + lrow;
            const int c8 = kk*4 + g;
            a[m] = *(const bf16x8*)(&xb[r*128 + ((c8 ^ (r & 15)) << 3)]);
        }
        #pragma unroll
        for (int n = 0; n < 4; ++n) {
            const int r = n*16 + lrow;
            const int c8 = kk*4 + g;
            b[n] = *(const bf16x8*)(&w2[r*128 + ((c8 ^ (r & 15)) << 3)]);
        }
        #pragma unroll
        for (int m = 0; m < 2; ++m)
            #pragma unroll
            for (int n = 0; n < 4; ++n)
                acc[m][n] = __builtin_amdgcn_mfma_f32_16x16x32_bf16(a[m], b[n], acc[m][n], 0, 0, 0);
    }

    // combine a/g -> proj bf16, via pbuf transpose for coalesced global write
    #pragma unroll
    for (int n = 0; n < 2; ++n) {
        const int c = n*16 + lrow;
        const float abc = ab[c], agbc = agb[c];
        #pragma unroll
        for (int m = 0; m < 2; ++m) {
            const int r0 = wid*32 + m*16 + g*4;
            #pragma unroll
            for (int q = 0; q < 4; ++q) {
                const float pa = acc[m][n][q]   + abc;
                const float pg = acc[m][n+2][q] + agbc;
                pbuf[c*136 + r0 + q] = f2bf(pa * sigm(pg));
            }
        }
    }
    __syncthreads();
    {
        const int c = t >> 3, q = t & 7;
        const uint4 d0 = *(const uint4*)(&pbuf[c*136 + q*16]);
        const uint4 d1 = *(const uint4*)(&pbuf[c*136 + q*16 + 8]);
        unsigned short* dst = proj + (size_t)c*LLF + rbase + q*16;
        *(uint4*)(dst)     = d0;
        *(uint4*)(dst + 8) = d1;
    }
}

// ---------------------------------------------------------------------------
// Kernel B: pair[c][i][j] = sum_l proj[c][i][l] * proj[c][j][l]  (NT GEMM)
// 128x128 tile, BK=32, 4 waves (2x2 of 64x64). fp32 accumulate.
// ---------------------------------------------------------------------------
__global__ __launch_bounds__(256, 2) void k_einsum(
    const unsigned short* __restrict__ proj, float* __restrict__ pair)
{
    __shared__ unsigned short At[128*32];
    __shared__ unsigned short Bt[128*32];

    const int bid = blockIdx.x;
    const int c = bid / 36, tt = bid - c*36;
    const int ti = tt / 6, tj = tt - ti*6;
    const unsigned short* pc = proj + (size_t)c * LLF;

    const int t = threadIdx.x;
    const int lane = t & 63, wid = t >> 6;
    const int lrow = lane & 15, g = lane >> 4;
    const int wr = wid >> 1, wc = wid & 1;

    f32x4 acc[4][4];
    #pragma unroll
    for (int m = 0; m < 4; ++m)
        #pragma unroll
        for (int n = 0; n < 4; ++n) acc[m][n] = (f32x4){0.f,0.f,0.f,0.f};

    const int srow = t >> 2, spart = t & 3;
    const unsigned short* gA = pc + (size_t)(ti*128 + srow)*LSZ + spart*8;
    const unsigned short* gB = pc + (size_t)(tj*128 + srow)*LSZ + spart*8;

    for (int kk = 0; kk < 24; ++kk) {
        __syncthreads();
        const int ko = kk*32;
        *(uint4*)(&At[srow*32 + spart*8])      = *(const uint4*)(gA + ko);
        *(uint4*)(&At[(srow+64)*32 + spart*8]) = *(const uint4*)(gA + (size_t)64*LSZ + ko);
        *(uint4*)(&Bt[srow*32 + spart*8])      = *(const uint4*)(gB + ko);
        *(uint4*)(&Bt[(srow+64)*32 + spart*8]) = *(const uint4*)(gB + (size_t)64*LSZ + ko);
        __syncthreads();

        bf16x8 a[4], b[4];
        #pragma unroll
        for (int m = 0; m < 4; ++m)
            a[m] = *(const bf16x8*)(&At[(wr*64 + m*16 + lrow)*32 + g*8]);
        #pragma unroll
        for (int n = 0; n < 4; ++n)
            b[n] = *(const bf16x8*)(&Bt[(wc*64 + n*16 + lrow)*32 + g*8]);
        #pragma unroll
        for (int m = 0; m < 4; ++m)
            #pragma unroll
            for (int n = 0; n < 4; ++n)
                acc[m][n] = __builtin_amdgcn_mfma_f32_16x16x32_bf16(a[m], b[n], acc[m][n], 0, 0, 0);
    }

    float* pout = pair + (size_t)c*LLF + (size_t)(ti*128 + wr*64)*LSZ + tj*128 + wc*64;
    #pragma unroll
    for (int m = 0; m < 4; ++m)
        #pragma unroll
        for (int n = 0; n < 4; ++n)
            #pragma unroll
            for (int q = 0; q < 4; ++q)
                pout[(size_t)(m*16 + g*4 + q)*LSZ + n*16 + lrow] = acc[m][n][q];
}

// ---------------------------------------------------------------------------
// Kernel C: out = (LN_P(pair) @ oW.T + ob) * sigmoid(LN_F(features) @ gW.T + gb)
// Both GEMMs via MFMA with identical C/D layout -> pure-register epilogue.
// ---------------------------------------------------------------------------
__global__ __launch_bounds__(256, 2) void k_final(
    const float* __restrict__ pair, const float* __restrict__ feat,
    const float* __restrict__ nw, const float* __restrict__ nb,
    const float* __restrict__ onw, const float* __restrict__ onb,
    const float* __restrict__ oW, const float* __restrict__ ob,
    const float* __restrict__ gW, const float* __restrict__ gb,
    float* __restrict__ out)
{
    __shared__ alignas(16) char smem[65536];
    float* pt = (float*)smem;                                 // [32][128] fp32
    unsigned short* lp  = (unsigned short*)smem;              // [128][40] bf16
    unsigned short* ow  = (unsigned short*)(smem + 10240);    // [128][40] bf16
    unsigned short* xbb = (unsigned short*)smem;              // [128][128] swizzled
    unsigned short* gwb = (unsigned short*)(smem + 32768);    // [128][128] swizzled

    const int t = threadIdx.x;
    const int rbase = blockIdx.x << 7;
    const int lane = t & 63, wid = t >> 6;
    const int lrow = lane & 15, g = lane >> 4;

    // ---- phase A: pair tile + LN over P=32 ----
    for (int u = t; u < 1024; u += 256) {
        const int cc = u >> 5, col = (u & 31) << 2;
        *(float4*)(&pt[cc*128 + col]) = *(const float4*)(pair + (size_t)cc*LLF + rbase + col);
    }
    __syncthreads();
    float vals[32];
    float s1 = 0.f, s2 = 0.f;
    if (t < 128) {
        #pragma unroll
        for (int cc = 0; cc < 32; ++cc) {
            const float x = pt[cc*128 + t];
            vals[cc] = x; s1 += x; s2 += x*x;
        }
    }
    __syncthreads();
    if (t < 128) {
        const float mu = s1 * (1.f/32.f);
        const float rstd = rsqrtf(s2 * (1.f/32.f) - mu*mu + 1e-5f);
        #pragma unroll
        for (int j = 0; j < 4; ++j) {
            float e[8];
            #pragma unroll
            for (int e2 = 0; e2 < 8; ++e2) {
                const int cc = j*8 + e2;
                e[e2] = (vals[cc]-mu)*rstd*onw[cc] + onb[cc];
            }
            uint4 o;
            o.x = pack2(e[0],e[1]); o.y = pack2(e[2],e[3]);
            o.z = pack2(e[4],e[5]); o.w = pack2(e[6],e[7]);
            *(uint4*)(&lp[t*40 + j*8]) = o;
        }
    }
    for (int u = t; u < 512; u += 256) {   // stage oW [128][32] as bf16
        const int r = u >> 2, c8 = u & 3;
        const float* src = oW + r*32 + c8*8;
        float4 f0 = *(const float4*)(src), f1 = *(const float4*)(src + 4);
        uint4 o;
        o.x = pack2(f0.x,f0.y); o.y = pack2(f0.z,f0.w);
        o.z = pack2(f1.x,f1.y); o.w = pack2(f1.z,f1.w);
        *(uint4*)(&ow[r*40 + c8*8]) = o;
    }
    __syncthreads();

    // ---- MFMA pass 1: out_lin = lp @ ow^T  (K=32) ----
    f32x4 acc_o[2][8];
    #pragma unroll
    for (int m = 0; m < 2; ++m)
        #pragma unroll
        for (int n = 0; n < 8; ++n) acc_o[m][n] = (f32x4){0.f,0.f,0.f,0.f};
    {
        bf16x8 a[2];
        #pragma unroll
        for (int m = 0; m < 2; ++m)
            a[m] = *(const bf16x8*)(&lp[(wid*32 + m*16 + lrow)*40 + g*8]);
        #pragma unroll
        for (int n = 0; n < 8; ++n) {
            const bf16x8 b = *(const bf16x8*)(&ow[(n*16 + lrow)*40 + g*8]);
            #pragma unroll
            for (int m = 0; m < 2; ++m)
                acc_o[m][n] = __builtin_amdgcn_mfma_f32_16x16x32_bf16(a[m], b, acc_o[m][n], 0, 0, 0);
        }
    }
    __syncthreads();

    // ---- phase B: re-LN features -> xbb, stage gW -> gwb ----
    {
        const int row = t >> 1, sub = t & 1;
        const float* frow = feat + (size_t)(rbase + row)*FD + sub*64;
        float4 v[16];
        float fs1 = 0.f, fs2 = 0.f;
        #pragma unroll
        for (int q = 0; q < 16; ++q) {
            v[q] = *(const float4*)(frow + q*4);
            fs1 += v[q].x + v[q].y + v[q].z + v[q].w;
            fs2 += v[q].x*v[q].x + v[q].y*v[q].y + v[q].z*v[q].z + v[q].w*v[q].w;
        }
        fs1 += __shfl_xor(fs1, 1);
        fs2 += __shfl_xor(fs2, 1);
        const float mu = fs1 * (1.f/128.f);
        const float rstd = rsqrtf(fs2 * (1.f/128.f) - mu*mu + 1e-5f);
        #pragma unroll
        for (int q = 0; q < 8; ++q) {
            const int k = sub*64 + q*8;
            float4 w0 = *(const float4*)(nw + k), w1 = *(const float4*)(nw + k + 4);
            float4 b0 = *(const float4*)(nb + k), b1 = *(const float4*)(nb + k + 4);
            float4 x0 = v[2*q], x1 = v[2*q+1];
            uint4 o;
            o.x = pack2((x0.x-mu)*rstd*w0.x + b0.x, (x0.y-mu)*rstd*w0.y + b0.y);
            o.y = pack2((x0.z-mu)*rstd*w0.z + b0.z, (x0.w-mu)*rstd*w0.w + b0.w);
            o.z = pack2((x1.x-mu)*rstd*w1.x + b1.x, (x1.y-mu)*rstd*w1.y + b1.y);
            o.w = pack2((x1.z-mu)*rstd*w1.z + b1.z, (x1.w-mu)*rstd*w1.w + b1.w);
            const int c8 = k >> 3;
            *(uint4*)(&xbb[row*128 + ((c8 ^ (row & 15)) << 3)]) = o;
        }
    }
    for (int u = t; u < 2048; u += 256) {   // gW [128][128] -> bf16 swizzled
        const int r = u >> 4, c8 = u & 15;
        const float* src = gW + r*128 + c8*8;
        float4 f0 = *(const float4*)(src), f1 = *(const float4*)(src + 4);
        uint4 o;
        o.x = pack2(f0.x,f0.y); o.y = pack2(f0.z,f0.w);
        o.z = pack2(f1.x,f1.y); o.w = pack2(f1.z,f1.w);
        *(uint4*)(&gwb[r*128 + ((c8 ^ (r & 15)) << 3)]) = o;
    }
    __syncthreads();

    // ---- MFMA pass 2: gate_lin = xbb @ gwb^T (K=128) ----
    f32x4 acc_g[2][8];
    #pragma unroll
    for (int m = 0; m < 2; ++m)
        #pragma unroll
        for (int n = 0; n < 8; ++n) acc_g[m][n] = (f32x4){0.f,0.f,0.f,0.f};
    #pragma unroll
    for (int kk = 0; kk < 4; ++kk) {
        bf16x8 a[2];
        #pragma unroll
        for (int m = 0; m < 2; ++m) {
            const int r = wid*32 + m*16 + lrow;
            const int c8 = kk*4 + g;
            a[m] = *(const bf16x8*)(&xbb[r*128 + ((c8 ^ (r & 15)) << 3)]);
        }
        #pragma unroll
        for (int n = 0; n < 8; ++n) {
            const int r = n*16 + lrow;
            const int c8 = kk*4 + g;
            const bf16x8 b = *(const bf16x8*)(&gwb[r*128 + ((c8 ^ (r & 15)) << 3)]);
            #pragma unroll
            for (int m = 0; m < 2; ++m)
                acc_g[m][n] = __builtin_amdgcn_mfma_f32_16x16x32_bf16(a[m], b, acc_g[m][n], 0, 0, 0);
        }
    }

    // ---- epilogue ----
    #pragma unroll
    for (int n = 0; n < 8; ++n) {
        const int f = n*16 + lrow;
        const float obf = ob[f], gbf = gb[f];
        #pragma unroll
        for (int m = 0; m < 2; ++m) {
            const int r0 = wid*32 + m*16 + g*4;
            #pragma unroll
            for (int q = 0; q < 4; ++q) {
                const float o  = acc_o[m][n][q] + obf;
                const float gt = sigm(acc_g[m][n][q] + gbf);
                out[(size_t)(rbase + r0 + q)*FD + f] = o * gt;
            }
        }
    }
}

extern "C" void kernel_launch(void* const* d_in, const int* in_sizes, int n_in,
                              void* d_out, int out_size, void* d_ws, size_t ws_size,
                              hipStream_t stream) {
    const float* feat = (const float*)d_in[0];
    const float* nw   = (const float*)d_in[1];
    const float* nb   = (const float*)d_in[2];
    const float* onw  = (const float*)d_in[3];
    const float* onb  = (const float*)d_in[4];
    const float* aW   = (const float*)d_in[5];
    const float* ab   = (const float*)d_in[6];
    const float* agW  = (const float*)d_in[7];
    const float* agb  = (const float*)d_in[8];
    const float* oW   = (const float*)d_in[9];
    const float* ob   = (const float*)d_in[10];
    const float* gW   = (const float*)d_in[11];
    const float* gb   = (const float*)d_in[12];

    unsigned short* proj = (unsigned short*)d_ws;                       // 32*LLF bf16
    float* pair = (float*)((char*)d_ws + (size_t)32*LLF*2);             // 32*LLF fp32
    float* outp = (float*)d_out;

    k_ln_proj<<<dim3(LLF/128), dim3(256), 0, stream>>>(feat, nw, nb, aW, ab, agW, agb, proj);
    k_einsum<<<dim3(32*36), dim3(256), 0, stream>>>(proj, pair);
    k_final<<<dim3(LLF/128), dim3(256), 0, stream>>>(pair, feat, nw, nb, onw, onb, oW, ob, gW, gb, outp);
}